// Round 1
// baseline (736.561 us; speedup 1.0000x reference)
//
#include <hip/hip_runtime.h>
#include <math.h>

// Problem constants (match reference)
#define BATCH 16384
#define DNUM  13
#define SNUM  26
#define FEAT  100000
#define KDIM  64          // = 32 float2 groups
#define RPW   2           // rows per wave
#define GB    7           // gather batch size (4 batches: 7,7,7,5)

// One 64-lane wave handles 2 batch rows.
// lane = 32*g + t : g = row group (0..1), t = k-group (0..31), k in {2t, 2t+1}.
// Rationale vs previous version (4 rows/wave, float4, full 26-deep unroll):
//  - 32 lanes/row doubles total waves: 8192 waves = 32/CU (at <=64 VGPR)
//    instead of the structural 4096-wave / 16-per-CU cap of 16 lanes/row.
//  - Batched gathers (GB=7) bound live registers: 14 result + 7 offset VGPRs
//    in flight, so no spills under __launch_bounds__(256,8)'s 64-VGPR cap.
//  - unsigned byte offsets -> saddr + u32 voffset addressing (1 VGPR/addr).
__global__ __launch_bounds__(256, 8) void fm_kernel(
    const float*  __restrict__ dense,   // [B, D]
    const int*    __restrict__ sparse,  // [B, S]
    const float*  __restrict__ w,       // [TOTAL, 1]
    const float2* __restrict__ V2,      // [TOTAL, 32] (float2 view of [TOTAL, 64])
    const float*  __restrict__ bias,    // [1]
    float*        __restrict__ out)     // [B]
{
    const int wave = (blockIdx.x * blockDim.x + threadIdx.x) >> 6;
    const int lane = threadIdx.x & 63;
    const int g    = lane >> 5;               // row within wave
    const int t    = lane & 31;               // k-group
    const int row  = wave * RPW + g;          // BATCH = 8192 waves * 2, no tail
    const int sbase = row * SNUM;

    // ---- first-order term, issued early to overlap with V gathers ----
    // lane t covers sparse field t (t<26); dense w for t<13. Also warms the
    // sparse row in L1 so the per-batch index reloads below are broadcast hits.
    float lin = 0.f;
    if (t < SNUM)
        lin = w[sparse[sbase + t] + DNUM + t * FEAT];
    const float* drow = dense + row * DNUM;
    if (t < DNUM)
        lin += drow[t] * w[t];

    float xv0 = 0.f, xv1 = 0.f, x2 = 0.f;

    // ---- sparse second-order: 26 coalesced float2 gathers, batches of 7 ----
    const char* Vb = (const char*)V2;
    #pragma unroll
    for (int b = 0; b < SNUM; b += GB) {
        const int n = (SNUM - b) < GB ? (SNUM - b) : GB;   // compile-time per batch
        float2 vb[GB];
        #pragma unroll
        for (int j = 0; j < GB; ++j) {
            if (j < n) {
                int gi = sparse[sbase + b + j] + DNUM + (b + j) * FEAT;
                unsigned off = ((unsigned)gi * 32u + (unsigned)t) * 8u;  // < 2^31
                vb[j] = *(const float2*)(Vb + off);
            }
        }
        #pragma unroll
        for (int j = 0; j < GB; ++j) {
            if (j < n) {
                xv0 += vb[j].x; xv1 += vb[j].y;
                x2  += vb[j].x * vb[j].x + vb[j].y * vb[j].y;
            }
        }
    }

    // ---- dense second-order: 13 rows, V[:13] hot in L1 ----
    #pragma unroll
    for (int d = 0; d < DNUM; ++d) {
        float  xd = drow[d];                  // broadcast within group
        float2 v  = V2[d * 32 + t];
        xv0 += xd * v.x; xv1 += xd * v.y;
        x2  += xd * xd * (v.x * v.x + v.y * v.y);
    }

    // ---- per-lane contribution: lane fully owns k in {2t, 2t+1} ----
    float part = 0.5f * (xv0 * xv0 + xv1 * xv1 - x2) + lin;

    // ---- 32-lane butterfly within the group (xor < 32 stays in-group) ----
    part += __shfl_xor(part, 1);
    part += __shfl_xor(part, 2);
    part += __shfl_xor(part, 4);
    part += __shfl_xor(part, 8);
    part += __shfl_xor(part, 16);

    if (t == 0) {
        float z = part + bias[0];
        out[row] = 1.0f / (1.0f + expf(-z));
    }
}

extern "C" void kernel_launch(void* const* d_in, const int* in_sizes, int n_in,
                              void* d_out, int out_size, void* d_ws, size_t ws_size,
                              hipStream_t stream) {
    const float*  dense  = (const float*)d_in[0];
    const int*    sparse = (const int*)d_in[1];
    const float*  w      = (const float*)d_in[2];
    const float2* V2     = (const float2*)d_in[3];
    const float*  bias   = (const float*)d_in[4];
    float* out = (float*)d_out;

    // 2 rows/wave, 4 waves/block -> 8 rows/block; 2048 blocks = 8 blocks/CU,
    // 32 waves/CU at <=64 VGPR (occupancy steps at VGPR 64/128/256).
    const int rows_per_block = (256 / 64) * RPW;
    const int grid = BATCH / rows_per_block;
    fm_kernel<<<grid, 256, 0, stream>>>(dense, sparse, w, V2, bias, out);
}